// Round 5
// baseline (754.111 us; speedup 1.0000x reference)
//
#include <hip/hip_runtime.h>
#include <hip/hip_bf16.h>

#define N_NODES 100000
#define N_EDGES 1600000
#define F_IN 128
#define HID 64
#define NC 10

#define BSH 7
#define BNODES 128                       // nodes per bucket = 1<<BSH
#define NB 782                           // ceil(N_NODES / 128)
#define PBLK 256                         // partition blocks
#define TILE ((N_EDGES + PBLK - 1) / PBLK)  // 6250 edges per block

#define XROWS 64
#define XPAD 132                         // 132*4 B = 528 B row: 16B-aligned, 2-way banks (free)

// ---------------- s1: global bucket histogram via LDS privatization
__global__ __launch_bounds__(256) void s1_bhist(const int* __restrict__ dst,
                                                int* __restrict__ bcount) {
    __shared__ int lh[NB];
    int t = threadIdx.x;
    for (int k = t; k < NB; k += 256) lh[k] = 0;
    __syncthreads();
    int b0 = blockIdx.x * TILE;
    int b1 = b0 + TILE < N_EDGES ? b0 + TILE : N_EDGES;
    for (int i = b0 + t; i < b1; i += 256)
        atomicAdd(&lh[dst[i] >> BSH], 1);
    __syncthreads();
    for (int k = t; k < NB; k += 256) {
        int c = lh[k];
        if (c) atomicAdd(&bcount[k], c);   // coalesced across lanes
    }
}

// ---------------- s2: exclusive scan of 782 bucket counts (1 block of 1024)
__global__ __launch_bounds__(1024) void s2_bscan(const int* __restrict__ bcount,
                                                 int* __restrict__ boffset,
                                                 int* __restrict__ bcursor,
                                                 int* __restrict__ row_start) {
    __shared__ int sm[1024];
    int t = threadIdx.x;
    int v = (t < NB) ? bcount[t] : 0;
    sm[t] = v;
    __syncthreads();
    for (int off = 1; off < 1024; off <<= 1) {
        int u = (t >= off) ? sm[t - off] : 0;
        __syncthreads();
        sm[t] += u;
        __syncthreads();
    }
    int excl = sm[t] - v;
    if (t < NB) {
        boffset[t] = excl;
        bcursor[t] = excl;
    }
    if (t == NB - 1) {
        boffset[NB] = sm[t];              // == N_EDGES
        row_start[N_NODES] = sm[t];       // sentinel
    }
}

// ---------------- s3: partition edges into bucket regions (block-reserved runs)
__global__ __launch_bounds__(256) void s3_part(const int* __restrict__ src,
                                               const int* __restrict__ dst,
                                               int* __restrict__ bcursor,
                                               int2* __restrict__ ppair) {
    __shared__ int lh[NB];     // histogram, then running cursor
    __shared__ int lbase[NB];  // reserved base per bucket
    int t = threadIdx.x;
    for (int k = t; k < NB; k += 256) lh[k] = 0;
    __syncthreads();
    int b0 = blockIdx.x * TILE;
    int b1 = b0 + TILE < N_EDGES ? b0 + TILE : N_EDGES;
    for (int i = b0 + t; i < b1; i += 256)
        atomicAdd(&lh[dst[i] >> BSH], 1);
    __syncthreads();
    for (int k = t; k < NB; k += 256) {
        int c = lh[k];
        lbase[k] = c ? atomicAdd(&bcursor[k], c) : 0;  // coalesced, with return
    }
    __syncthreads();
    for (int k = t; k < NB; k += 256) lh[k] = lbase[k];
    __syncthreads();
    for (int i = b0 + t; i < b1; i += 256) {
        int d = dst[i];
        int slot = atomicAdd(&lh[d >> BSH], 1);        // LDS atomic (fast)
        ppair[slot] = make_int2(src[i], d);
    }
}

// ---------------- s4: per-bucket CSR finalize (row_start, dis, csr)
__global__ __launch_bounds__(256) void s4_build(const int2* __restrict__ ppair,
                                                const int* __restrict__ boffset,
                                                int* __restrict__ row_start,
                                                float* __restrict__ dis,
                                                int* __restrict__ csr) {
    __shared__ int h[BNODES];
    __shared__ int sc[BNODES];
    __shared__ int lcur[BNODES];
    int t = threadIdx.x;
    int b = blockIdx.x;
    int base = boffset[b];
    int cnt = boffset[b + 1] - base;
    int nodes0 = b << BSH;
    if (t < BNODES) h[t] = 0;
    __syncthreads();
    for (int j = t; j < cnt; j += 256)
        atomicAdd(&h[ppair[base + j].y - nodes0], 1);
    __syncthreads();
    if (t < BNODES) sc[t] = h[t];
    __syncthreads();
    for (int off = 1; off < BNODES; off <<= 1) {
        int u = (t < BNODES && t >= off) ? sc[t - off] : 0;
        __syncthreads();
        if (t < BNODES) sc[t] += u;
        __syncthreads();
    }
    if (t < BNODES) {
        int node = nodes0 + t;
        int excl = sc[t] - h[t];
        if (node < N_NODES) {
            row_start[node] = base + excl;
            dis[node] = rsqrtf((float)(h[t] + 1));
            lcur[t] = base + excl;
        }
    }
    __syncthreads();
    for (int j = t; j < cnt; j += 256) {
        int2 p = ppair[base + j];
        int slot = atomicAdd(&lcur[p.y - nodes0], 1);   // LDS atomic
        csr[slot] = p.x;
    }
}

// ---------------- hxs = (x @ W1) * dis ; 64x64 LDS-tiled, 4x4 per thread
__global__ __launch_bounds__(256) void k_xw(const float* __restrict__ x,
                                            const float* __restrict__ W1,
                                            const float* __restrict__ dis,
                                            float* __restrict__ hxs) {
    __shared__ float Ws[F_IN * HID];      // 32 KB, [k][c] row-major (== W1 layout)
    __shared__ float Xs[XROWS * XPAD];    // 33 KB, [n][k] padded
    int t = threadIdx.x;
    int base = blockIdx.x * XROWS;

    for (int i = t; i < (F_IN * HID) / 4; i += 256)
        reinterpret_cast<float4*>(Ws)[i] = reinterpret_cast<const float4*>(W1)[i];

    for (int i = t; i < XROWS * (F_IN / 4); i += 256) {
        int n = i >> 5;           // 32 float4 per row
        int kq = i & 31;
        int gn = base + n;
        float4 v = make_float4(0.f, 0.f, 0.f, 0.f);
        if (gn < N_NODES)
            v = reinterpret_cast<const float4*>(x + (size_t)gn * F_IN)[kq];
        *reinterpret_cast<float4*>(&Xs[n * XPAD + kq * 4]) = v;
    }
    __syncthreads();

    int cg = (t & 15) * 4;        // col base: 16 groups x 4 cols
    int ng = (t >> 4) * 4;        // node base: 16 groups x 4 nodes
    float acc[4][4] = {};
#pragma unroll
    for (int k0 = 0; k0 < F_IN; k0 += 4) {
        float4 wv[4];
#pragma unroll
        for (int kk = 0; kk < 4; ++kk)
            wv[kk] = *reinterpret_cast<const float4*>(&Ws[(k0 + kk) * HID + cg]);
        const float* wp = reinterpret_cast<const float*>(wv);  // wp[kk*4+c]
#pragma unroll
        for (int i = 0; i < 4; ++i) {
            float4 xv = *reinterpret_cast<const float4*>(&Xs[(ng + i) * XPAD + k0]);
            const float xa[4] = {xv.x, xv.y, xv.z, xv.w};
#pragma unroll
            for (int kk = 0; kk < 4; ++kk)
#pragma unroll
                for (int c = 0; c < 4; ++c)
                    acc[i][c] = fmaf(xa[kk], wp[kk * 4 + c], acc[i][c]);
        }
    }

#pragma unroll
    for (int i = 0; i < 4; ++i) {
        int n = base + ng + i;
        if (n < N_NODES) {
            float d = dis[n];
            float4 o = make_float4(acc[i][0] * d, acc[i][1] * d,
                                   acc[i][2] * d, acc[i][3] * d);
            *reinterpret_cast<float4*>(&hxs[(size_t)n * HID + cg]) = o;
        }
    }
}

// ---------------- layer-1 aggregate: gather over CSR, one wave per node
__global__ __launch_bounds__(256) void k_agg1(const int* __restrict__ row_start,
                                              const int* __restrict__ csr,
                                              const float* __restrict__ dis,
                                              const float* __restrict__ hxs,
                                              float* __restrict__ h1) {
    int lane = threadIdx.x & 63;
    int node = (blockIdx.x * blockDim.x + threadIdx.x) >> 6;
    if (node >= N_NODES) return;
    int beg = row_start[node], end = row_start[node + 1];
    float acc = hxs[(size_t)node * HID + lane];
    int j = beg;
    for (; j + 4 <= end; j += 4) {
        int s0 = csr[j], s1 = csr[j + 1], s2 = csr[j + 2], s3 = csr[j + 3];
        acc += hxs[(size_t)s0 * HID + lane];
        acc += hxs[(size_t)s1 * HID + lane];
        acc += hxs[(size_t)s2 * HID + lane];
        acc += hxs[(size_t)s3 * HID + lane];
    }
    for (; j < end; ++j)
        acc += hxs[(size_t)csr[j] * HID + lane];
    h1[(size_t)node * HID + lane] = acc * dis[node];
}

// ---------------- h2s = (relu(h1 + b1) @ W2) * dis[n], float4 h1 reads
__global__ __launch_bounds__(256) void k_h2x(const float* __restrict__ h1,
                                             const float* __restrict__ b1,
                                             const float* __restrict__ W2,
                                             const float* __restrict__ dis,
                                             float* __restrict__ h2s) {
    __shared__ float W2s[HID * NC];
    __shared__ float b1s[HID];
    for (int i = threadIdx.x; i < HID * NC; i += 256) W2s[i] = W2[i];
    if (threadIdx.x < HID) b1s[threadIdx.x] = b1[threadIdx.x];
    __syncthreads();
    int c  = threadIdx.x & 15;   // 16 lanes per row, 10 active
    int rg = threadIdx.x >> 4;   // 16 rows per block
    int n  = blockIdx.x * 16 + rg;
    if (n >= N_NODES || c >= NC) return;
    const float* hr = h1 + (size_t)n * HID;
    float acc = 0.f;
#pragma unroll
    for (int kq = 0; kq < HID / 4; ++kq) {
        float4 hv = *reinterpret_cast<const float4*>(&hr[kq * 4]);
        const float ha[4] = {hv.x, hv.y, hv.z, hv.w};
#pragma unroll
        for (int kk = 0; kk < 4; ++kk) {
            int k = kq * 4 + kk;
            float v = ha[kk] + b1s[k];
            v = v > 0.f ? v : 0.f;
            acc = fmaf(v, W2s[k * NC + c], acc);
        }
    }
    h2s[(size_t)n * NC + c] = acc * dis[n];
}

// ---------------- layer-2 aggregate + bias + log_softmax, fused
__global__ __launch_bounds__(256) void k_agg2f(const int* __restrict__ row_start,
                                               const int* __restrict__ csr,
                                               const float* __restrict__ dis,
                                               const float* __restrict__ h2s,
                                               const float* __restrict__ b2,
                                               float* __restrict__ out) {
    int c = threadIdx.x & 15;  // 16 lanes per node, 10 active
    int node = (blockIdx.x * blockDim.x + threadIdx.x) >> 4;
    if (node >= N_NODES) return;
    int beg = row_start[node], end = row_start[node + 1];
    float acc;
    if (c < NC) {
        acc = h2s[(size_t)node * NC + c];
        int j = beg;
        for (; j + 2 <= end; j += 2) {
            int s0 = csr[j], s1 = csr[j + 1];
            acc += h2s[(size_t)s0 * NC + c];
            acc += h2s[(size_t)s1 * NC + c];
        }
        for (; j < end; ++j)
            acc += h2s[(size_t)csr[j] * NC + c];
        acc = acc * dis[node] + b2[c];
    } else {
        acc = -1e30f;
    }
    float m = acc;
#pragma unroll
    for (int off = 8; off >= 1; off >>= 1)
        m = fmaxf(m, __shfl_xor(m, off, 16));
    float e = (c < NC) ? expf(acc - m) : 0.f;
    float ssum = e;
#pragma unroll
    for (int off = 8; off >= 1; off >>= 1)
        ssum += __shfl_xor(ssum, off, 16);
    float lse = m + logf(ssum);
    if (c < NC) out[(size_t)node * NC + c] = acc - lse;
}

static inline size_t align16(size_t v) { return (v + 15) & ~(size_t)15; }

extern "C" void kernel_launch(void* const* d_in, const int* in_sizes, int n_in,
                              void* d_out, int out_size, void* d_ws, size_t ws_size,
                              hipStream_t stream) {
    const float* x  = (const float*)d_in[0];
    const int*   ei = (const int*)d_in[1];    // [2, E] int32 (JAX x64 off)
    const float* W1 = (const float*)d_in[2];
    const float* b1 = (const float*)d_in[3];
    const float* W2 = (const float*)d_in[4];
    const float* b2 = (const float*)d_in[5];
    float* out = (float*)d_out;

    const int* src = ei;             // edge_index[0]
    const int* dst = ei + N_EDGES;   // edge_index[1]

    char* ws = (char*)d_ws;
    size_t off = 0;
    int* bcount = (int*)(ws + off);     off = align16(off + 4u * NB);
    int* boffset = (int*)(ws + off);    off = align16(off + 4u * (NB + 1));
    int* bcursor = (int*)(ws + off);    off = align16(off + 4u * NB);
    int* row_start = (int*)(ws + off);  off = align16(off + 4u * (N_NODES + 1));
    float* dis = (float*)(ws + off);    off = align16(off + 4u * N_NODES);
    int* csr = (int*)(ws + off);        off = align16(off + 4u * N_EDGES);
    float* hxs = (float*)(ws + off);    off = align16(off + 4u * (size_t)N_NODES * HID);
    float* h1  = (float*)(ws + off);    off = align16(off + 4u * (size_t)N_NODES * HID);
    int2* ppair = (int2*)h1;            // alias: h1 not written until k_agg1
    float* h2s = hxs;                   // alias: hxs dead after k_agg1

    hipMemsetAsync(bcount, 0, 4u * NB, stream);
    s1_bhist<<<PBLK, 256, 0, stream>>>(dst, bcount);
    s2_bscan<<<1, 1024, 0, stream>>>(bcount, boffset, bcursor, row_start);
    s3_part<<<PBLK, 256, 0, stream>>>(src, dst, bcursor, ppair);
    s4_build<<<NB, 256, 0, stream>>>(ppair, boffset, row_start, dis, csr);
    k_xw<<<(N_NODES + XROWS - 1) / XROWS, 256, 0, stream>>>(x, W1, dis, hxs);
    k_agg1<<<(N_NODES * 64) / 256, 256, 0, stream>>>(row_start, csr, dis, hxs, h1);
    k_h2x<<<(N_NODES + 15) / 16, 256, 0, stream>>>(h1, b1, W2, dis, h2s);
    k_agg2f<<<(N_NODES * 16) / 256, 256, 0, stream>>>(row_start, csr, dis, h2s, b2, out);
}

// Round 6
// 236.777 us; speedup vs baseline: 3.1849x; 3.1849x over previous
//
#include <hip/hip_runtime.h>
#include <hip/hip_bf16.h>

#define N_NODES 100000
#define N_EDGES 1600000
#define F_IN 128
#define HID 64
#define NC 10

#define BSH 7
#define BNODES 128                       // nodes per bucket = 1<<BSH
#define NB 782                           // ceil(N_NODES / 128)
#define PBLK 256                         // partition blocks
#define TILE ((N_EDGES + PBLK - 1) / PBLK)  // 6250 edges per block

#define XROWS 64
#define XPAD 132                         // 528 B row: 16B-aligned, 2-way banks (free)

// ---------------- s1: global bucket histogram via LDS privatization
__global__ __launch_bounds__(256) void s1_bhist(const int* __restrict__ dst,
                                                int* __restrict__ bcount) {
    __shared__ int lh[NB];
    int t = threadIdx.x;
    for (int k = t; k < NB; k += 256) lh[k] = 0;
    __syncthreads();
    int b0 = blockIdx.x * TILE;
    int b1 = b0 + TILE < N_EDGES ? b0 + TILE : N_EDGES;
    for (int i = b0 + t; i < b1; i += 256)
        atomicAdd(&lh[dst[i] >> BSH], 1);
    __syncthreads();
    for (int k = t; k < NB; k += 256) {
        int c = lh[k];
        if (c) atomicAdd(&bcount[k], c);   // coalesced across lanes
    }
}

// ---------------- s2: exclusive scan of 782 bucket counts (1 block of 1024)
__global__ __launch_bounds__(1024) void s2_bscan(const int* __restrict__ bcount,
                                                 int* __restrict__ boffset,
                                                 int* __restrict__ bcursor,
                                                 int* __restrict__ row_start) {
    __shared__ int sm[1024];
    int t = threadIdx.x;
    int v = (t < NB) ? bcount[t] : 0;
    sm[t] = v;
    __syncthreads();
    for (int off = 1; off < 1024; off <<= 1) {
        int u = (t >= off) ? sm[t - off] : 0;
        __syncthreads();
        sm[t] += u;
        __syncthreads();
    }
    int excl = sm[t] - v;
    if (t < NB) {
        boffset[t] = excl;
        bcursor[t] = excl;
    }
    if (t == NB - 1) {
        boffset[NB] = sm[t];              // == N_EDGES
        row_start[N_NODES] = sm[t];       // sentinel
    }
}

// ---------------- s3: partition edges into bucket regions (block-reserved runs)
__global__ __launch_bounds__(256) void s3_part(const int* __restrict__ src,
                                               const int* __restrict__ dst,
                                               int* __restrict__ bcursor,
                                               int2* __restrict__ ppair) {
    __shared__ int lh[NB];     // histogram, then running cursor
    __shared__ int lbase[NB];  // reserved base per bucket
    int t = threadIdx.x;
    for (int k = t; k < NB; k += 256) lh[k] = 0;
    __syncthreads();
    int b0 = blockIdx.x * TILE;
    int b1 = b0 + TILE < N_EDGES ? b0 + TILE : N_EDGES;
    for (int i = b0 + t; i < b1; i += 256)
        atomicAdd(&lh[dst[i] >> BSH], 1);
    __syncthreads();
    for (int k = t; k < NB; k += 256) {
        int c = lh[k];
        lbase[k] = c ? atomicAdd(&bcursor[k], c) : 0;  // coalesced, with return
    }
    __syncthreads();
    for (int k = t; k < NB; k += 256) lh[k] = lbase[k];
    __syncthreads();
    for (int i = b0 + t; i < b1; i += 256) {
        int d = dst[i];
        int slot = atomicAdd(&lh[d >> BSH], 1);        // LDS atomic (fast)
        ppair[slot] = make_int2(src[i], d);
    }
}

// ---------------- s4: per-bucket CSR finalize (row_start, dis, csr)
__global__ __launch_bounds__(256) void s4_build(const int2* __restrict__ ppair,
                                                const int* __restrict__ boffset,
                                                int* __restrict__ row_start,
                                                float* __restrict__ dis,
                                                int* __restrict__ csr) {
    __shared__ int h[BNODES];
    __shared__ int sc[BNODES];
    __shared__ int lcur[BNODES];
    int t = threadIdx.x;
    int b = blockIdx.x;
    int base = boffset[b];
    int cnt = boffset[b + 1] - base;
    int nodes0 = b << BSH;
    if (t < BNODES) h[t] = 0;
    __syncthreads();
    for (int j = t; j < cnt; j += 256)
        atomicAdd(&h[ppair[base + j].y - nodes0], 1);
    __syncthreads();
    if (t < BNODES) sc[t] = h[t];
    __syncthreads();
    for (int off = 1; off < BNODES; off <<= 1) {
        int u = (t < BNODES && t >= off) ? sc[t - off] : 0;
        __syncthreads();
        if (t < BNODES) sc[t] += u;
        __syncthreads();
    }
    if (t < BNODES) {
        int node = nodes0 + t;
        int excl = sc[t] - h[t];
        if (node < N_NODES) {
            row_start[node] = base + excl;
            dis[node] = rsqrtf((float)(h[t] + 1));
            lcur[t] = base + excl;
        }
    }
    __syncthreads();
    for (int j = t; j < cnt; j += 256) {
        int2 p = ppair[base + j];
        int slot = atomicAdd(&lcur[p.y - nodes0], 1);   // LDS atomic
        csr[slot] = p.x;
    }
}

__device__ __forceinline__ float4 fma4(float s, float4 w, float4 a) {
    a.x = fmaf(s, w.x, a.x);
    a.y = fmaf(s, w.y, a.y);
    a.z = fmaf(s, w.z, a.z);
    a.w = fmaf(s, w.w, a.w);
    return a;
}

// ---------------- hxs = (x @ W1) * dis ; 64x64 LDS-tiled, 4x4 per thread
// All per-thread state in NAMED float4s (no local arrays -> no scratch).
__global__ __launch_bounds__(256) void k_xw(const float* __restrict__ x,
                                            const float* __restrict__ W1,
                                            const float* __restrict__ dis,
                                            float* __restrict__ hxs) {
    __shared__ float Ws[F_IN * HID];      // 32 KB, [k][c] (== W1 layout)
    __shared__ float Xs[XROWS * XPAD];    // 33 KB, [n][k] padded
    int t = threadIdx.x;
    int base = blockIdx.x * XROWS;

    for (int i = t; i < (F_IN * HID) / 4; i += 256)
        reinterpret_cast<float4*>(Ws)[i] = reinterpret_cast<const float4*>(W1)[i];

    for (int i = t; i < XROWS * (F_IN / 4); i += 256) {
        int n = i >> 5;           // 32 float4 per row
        int kq = i & 31;
        int gn = base + n;
        float4 v = make_float4(0.f, 0.f, 0.f, 0.f);
        if (gn < N_NODES)
            v = reinterpret_cast<const float4*>(x + (size_t)gn * F_IN)[kq];
        *reinterpret_cast<float4*>(&Xs[n * XPAD + kq * 4]) = v;
    }
    __syncthreads();

    int cg = (t & 15) * 4;        // col base: 16 groups x 4 cols
    int ng = (t >> 4) * 4;        // node base: 16 groups x 4 nodes
    float4 a0 = make_float4(0.f, 0.f, 0.f, 0.f);
    float4 a1 = a0, a2 = a0, a3 = a0;

#pragma unroll 4
    for (int k0 = 0; k0 < F_IN; k0 += 4) {
        float4 w0 = *reinterpret_cast<const float4*>(&Ws[(k0 + 0) * HID + cg]);
        float4 w1 = *reinterpret_cast<const float4*>(&Ws[(k0 + 1) * HID + cg]);
        float4 w2 = *reinterpret_cast<const float4*>(&Ws[(k0 + 2) * HID + cg]);
        float4 w3 = *reinterpret_cast<const float4*>(&Ws[(k0 + 3) * HID + cg]);
        float4 x0 = *reinterpret_cast<const float4*>(&Xs[(ng + 0) * XPAD + k0]);
        float4 x1 = *reinterpret_cast<const float4*>(&Xs[(ng + 1) * XPAD + k0]);
        float4 x2 = *reinterpret_cast<const float4*>(&Xs[(ng + 2) * XPAD + k0]);
        float4 x3 = *reinterpret_cast<const float4*>(&Xs[(ng + 3) * XPAD + k0]);
        a0 = fma4(x0.x, w0, a0); a0 = fma4(x0.y, w1, a0);
        a0 = fma4(x0.z, w2, a0); a0 = fma4(x0.w, w3, a0);
        a1 = fma4(x1.x, w0, a1); a1 = fma4(x1.y, w1, a1);
        a1 = fma4(x1.z, w2, a1); a1 = fma4(x1.w, w3, a1);
        a2 = fma4(x2.x, w0, a2); a2 = fma4(x2.y, w1, a2);
        a2 = fma4(x2.z, w2, a2); a2 = fma4(x2.w, w3, a2);
        a3 = fma4(x3.x, w0, a3); a3 = fma4(x3.y, w1, a3);
        a3 = fma4(x3.z, w2, a3); a3 = fma4(x3.w, w3, a3);
    }

    int n0 = base + ng;
    if (n0 + 0 < N_NODES) {
        float d = dis[n0 + 0];
        *reinterpret_cast<float4*>(&hxs[(size_t)(n0 + 0) * HID + cg]) =
            make_float4(a0.x * d, a0.y * d, a0.z * d, a0.w * d);
    }
    if (n0 + 1 < N_NODES) {
        float d = dis[n0 + 1];
        *reinterpret_cast<float4*>(&hxs[(size_t)(n0 + 1) * HID + cg]) =
            make_float4(a1.x * d, a1.y * d, a1.z * d, a1.w * d);
    }
    if (n0 + 2 < N_NODES) {
        float d = dis[n0 + 2];
        *reinterpret_cast<float4*>(&hxs[(size_t)(n0 + 2) * HID + cg]) =
            make_float4(a2.x * d, a2.y * d, a2.z * d, a2.w * d);
    }
    if (n0 + 3 < N_NODES) {
        float d = dis[n0 + 3];
        *reinterpret_cast<float4*>(&hxs[(size_t)(n0 + 3) * HID + cg]) =
            make_float4(a3.x * d, a3.y * d, a3.z * d, a3.w * d);
    }
}

// ---------------- layer-1 aggregate: gather over CSR, one wave per node
__global__ __launch_bounds__(256) void k_agg1(const int* __restrict__ row_start,
                                              const int* __restrict__ csr,
                                              const float* __restrict__ dis,
                                              const float* __restrict__ hxs,
                                              float* __restrict__ h1) {
    int lane = threadIdx.x & 63;
    int node = (blockIdx.x * blockDim.x + threadIdx.x) >> 6;
    if (node >= N_NODES) return;
    int beg = row_start[node], end = row_start[node + 1];
    float acc = hxs[(size_t)node * HID + lane];
    int j = beg;
    for (; j + 4 <= end; j += 4) {
        int s0 = csr[j], s1 = csr[j + 1], s2 = csr[j + 2], s3 = csr[j + 3];
        acc += hxs[(size_t)s0 * HID + lane];
        acc += hxs[(size_t)s1 * HID + lane];
        acc += hxs[(size_t)s2 * HID + lane];
        acc += hxs[(size_t)s3 * HID + lane];
    }
    for (; j < end; ++j)
        acc += hxs[(size_t)csr[j] * HID + lane];
    h1[(size_t)node * HID + lane] = acc * dis[node];
}

// ---------------- h2s = (relu(h1 + b1) @ W2) * dis[n], float4 h1 reads
__global__ __launch_bounds__(256) void k_h2x(const float* __restrict__ h1,
                                             const float* __restrict__ b1,
                                             const float* __restrict__ W2,
                                             const float* __restrict__ dis,
                                             float* __restrict__ h2s) {
    __shared__ float W2s[HID * NC];
    __shared__ float b1s[HID];
    for (int i = threadIdx.x; i < HID * NC; i += 256) W2s[i] = W2[i];
    if (threadIdx.x < HID) b1s[threadIdx.x] = b1[threadIdx.x];
    __syncthreads();
    int c  = threadIdx.x & 15;   // 16 lanes per row, 10 active
    int rg = threadIdx.x >> 4;   // 16 rows per block
    int n  = blockIdx.x * 16 + rg;
    if (n >= N_NODES || c >= NC) return;
    const float* hr = h1 + (size_t)n * HID;
    float acc = 0.f;
#pragma unroll
    for (int kq = 0; kq < HID / 4; ++kq) {
        float4 hv = *reinterpret_cast<const float4*>(&hr[kq * 4]);
        float v0 = hv.x + b1s[kq * 4 + 0]; v0 = v0 > 0.f ? v0 : 0.f;
        float v1 = hv.y + b1s[kq * 4 + 1]; v1 = v1 > 0.f ? v1 : 0.f;
        float v2 = hv.z + b1s[kq * 4 + 2]; v2 = v2 > 0.f ? v2 : 0.f;
        float v3 = hv.w + b1s[kq * 4 + 3]; v3 = v3 > 0.f ? v3 : 0.f;
        acc = fmaf(v0, W2s[(kq * 4 + 0) * NC + c], acc);
        acc = fmaf(v1, W2s[(kq * 4 + 1) * NC + c], acc);
        acc = fmaf(v2, W2s[(kq * 4 + 2) * NC + c], acc);
        acc = fmaf(v3, W2s[(kq * 4 + 3) * NC + c], acc);
    }
    h2s[(size_t)n * NC + c] = acc * dis[n];
}

// ---------------- layer-2 aggregate + bias + log_softmax, fused
__global__ __launch_bounds__(256) void k_agg2f(const int* __restrict__ row_start,
                                               const int* __restrict__ csr,
                                               const float* __restrict__ dis,
                                               const float* __restrict__ h2s,
                                               const float* __restrict__ b2,
                                               float* __restrict__ out) {
    int c = threadIdx.x & 15;  // 16 lanes per node, 10 active
    int node = (blockIdx.x * blockDim.x + threadIdx.x) >> 4;
    if (node >= N_NODES) return;
    int beg = row_start[node], end = row_start[node + 1];
    float acc;
    if (c < NC) {
        acc = h2s[(size_t)node * NC + c];
        int j = beg;
        for (; j + 2 <= end; j += 2) {
            int s0 = csr[j], s1 = csr[j + 1];
            acc += h2s[(size_t)s0 * NC + c];
            acc += h2s[(size_t)s1 * NC + c];
        }
        for (; j < end; ++j)
            acc += h2s[(size_t)csr[j] * NC + c];
        acc = acc * dis[node] + b2[c];
    } else {
        acc = -1e30f;
    }
    float m = acc;
#pragma unroll
    for (int off = 8; off >= 1; off >>= 1)
        m = fmaxf(m, __shfl_xor(m, off, 16));
    float e = (c < NC) ? expf(acc - m) : 0.f;
    float ssum = e;
#pragma unroll
    for (int off = 8; off >= 1; off >>= 1)
        ssum += __shfl_xor(ssum, off, 16);
    float lse = m + logf(ssum);
    if (c < NC) out[(size_t)node * NC + c] = acc - lse;
}

static inline size_t align16(size_t v) { return (v + 15) & ~(size_t)15; }

extern "C" void kernel_launch(void* const* d_in, const int* in_sizes, int n_in,
                              void* d_out, int out_size, void* d_ws, size_t ws_size,
                              hipStream_t stream) {
    const float* x  = (const float*)d_in[0];
    const int*   ei = (const int*)d_in[1];    // [2, E] int32 (JAX x64 off)
    const float* W1 = (const float*)d_in[2];
    const float* b1 = (const float*)d_in[3];
    const float* W2 = (const float*)d_in[4];
    const float* b2 = (const float*)d_in[5];
    float* out = (float*)d_out;

    const int* src = ei;             // edge_index[0]
    const int* dst = ei + N_EDGES;   // edge_index[1]

    char* ws = (char*)d_ws;
    size_t off = 0;
    int* bcount = (int*)(ws + off);     off = align16(off + 4u * NB);
    int* boffset = (int*)(ws + off);    off = align16(off + 4u * (NB + 1));
    int* bcursor = (int*)(ws + off);    off = align16(off + 4u * NB);
    int* row_start = (int*)(ws + off);  off = align16(off + 4u * (N_NODES + 1));
    float* dis = (float*)(ws + off);    off = align16(off + 4u * N_NODES);
    int* csr = (int*)(ws + off);        off = align16(off + 4u * N_EDGES);
    float* hxs = (float*)(ws + off);    off = align16(off + 4u * (size_t)N_NODES * HID);
    float* h1  = (float*)(ws + off);    off = align16(off + 4u * (size_t)N_NODES * HID);
    int2* ppair = (int2*)h1;            // alias: h1 not written until k_agg1
    float* h2s = hxs;                   // alias: hxs dead after k_agg1

    hipMemsetAsync(bcount, 0, 4u * NB, stream);
    s1_bhist<<<PBLK, 256, 0, stream>>>(dst, bcount);
    s2_bscan<<<1, 1024, 0, stream>>>(bcount, boffset, bcursor, row_start);
    s3_part<<<PBLK, 256, 0, stream>>>(src, dst, bcursor, ppair);
    s4_build<<<NB, 256, 0, stream>>>(ppair, boffset, row_start, dis, csr);
    k_xw<<<(N_NODES + XROWS - 1) / XROWS, 256, 0, stream>>>(x, W1, dis, hxs);
    k_agg1<<<(N_NODES * 64) / 256, 256, 0, stream>>>(row_start, csr, dis, hxs, h1);
    k_h2x<<<(N_NODES + 15) / 16, 256, 0, stream>>>(h1, b1, W2, dis, h2s);
    k_agg2f<<<(N_NODES * 16) / 256, 256, 0, stream>>>(row_start, csr, dis, h2s, b2, out);
}

// Round 7
// 218.774 us; speedup vs baseline: 3.4470x; 1.0823x over previous
//
#include <hip/hip_runtime.h>
#include <hip/hip_bf16.h>

#define N_NODES 100000
#define N_EDGES 1600000
#define F_IN 128
#define HID 64
#define NC 10

#define BSH 7
#define BNODES 128                       // nodes per bucket = 1<<BSH
#define NB 782                           // ceil(N_NODES / 128)
#define PBLK 256                         // partition blocks
#define TILE ((N_EDGES + PBLK - 1) / PBLK)  // 6250 edges per block

#define XROWS 64
#define XPAD 132                         // 528 B row: 16B-aligned, 2-way banks (free)

__device__ __forceinline__ unsigned short f2bf(float f) {
    unsigned u = __float_as_uint(f);
    u += 0x7FFFu + ((u >> 16) & 1u);     // round-to-nearest-even
    return (unsigned short)(u >> 16);
}
__device__ __forceinline__ float bf2f(unsigned short b) {
    return __uint_as_float(((unsigned)b) << 16);
}

// ---------------- s1: global bucket histogram via LDS privatization
__global__ __launch_bounds__(256) void s1_bhist(const int* __restrict__ dst,
                                                int* __restrict__ bcount) {
    __shared__ int lh[NB];
    int t = threadIdx.x;
    for (int k = t; k < NB; k += 256) lh[k] = 0;
    __syncthreads();
    int b0 = blockIdx.x * TILE;
    int b1 = b0 + TILE < N_EDGES ? b0 + TILE : N_EDGES;
    for (int i = b0 + t; i < b1; i += 256)
        atomicAdd(&lh[dst[i] >> BSH], 1);
    __syncthreads();
    for (int k = t; k < NB; k += 256) {
        int c = lh[k];
        if (c) atomicAdd(&bcount[k], c);   // coalesced across lanes
    }
}

// ---------------- s2: exclusive scan of 782 bucket counts (1 block of 1024)
__global__ __launch_bounds__(1024) void s2_bscan(const int* __restrict__ bcount,
                                                 int* __restrict__ boffset,
                                                 int* __restrict__ bcursor,
                                                 int* __restrict__ row_start) {
    __shared__ int sm[1024];
    int t = threadIdx.x;
    int v = (t < NB) ? bcount[t] : 0;
    sm[t] = v;
    __syncthreads();
    for (int off = 1; off < 1024; off <<= 1) {
        int u = (t >= off) ? sm[t - off] : 0;
        __syncthreads();
        sm[t] += u;
        __syncthreads();
    }
    int excl = sm[t] - v;
    if (t < NB) {
        boffset[t] = excl;
        bcursor[t] = excl;
    }
    if (t == NB - 1) {
        boffset[NB] = sm[t];              // == N_EDGES
        row_start[N_NODES] = sm[t];       // sentinel
    }
}

// ---------------- s3: partition edges into bucket regions (block-reserved runs)
__global__ __launch_bounds__(256) void s3_part(const int* __restrict__ src,
                                               const int* __restrict__ dst,
                                               int* __restrict__ bcursor,
                                               int2* __restrict__ ppair) {
    __shared__ int lh[NB];     // histogram, then running cursor
    __shared__ int lbase[NB];  // reserved base per bucket
    int t = threadIdx.x;
    for (int k = t; k < NB; k += 256) lh[k] = 0;
    __syncthreads();
    int b0 = blockIdx.x * TILE;
    int b1 = b0 + TILE < N_EDGES ? b0 + TILE : N_EDGES;
    for (int i = b0 + t; i < b1; i += 256)
        atomicAdd(&lh[dst[i] >> BSH], 1);
    __syncthreads();
    for (int k = t; k < NB; k += 256) {
        int c = lh[k];
        lbase[k] = c ? atomicAdd(&bcursor[k], c) : 0;  // coalesced, with return
    }
    __syncthreads();
    for (int k = t; k < NB; k += 256) lh[k] = lbase[k];
    __syncthreads();
    for (int i = b0 + t; i < b1; i += 256) {
        int d = dst[i];
        int slot = atomicAdd(&lh[d >> BSH], 1);        // LDS atomic (fast)
        ppair[slot] = make_int2(src[i], d);
    }
}

// ---------------- s4: per-bucket CSR finalize (row_start, dis, csr)
__global__ __launch_bounds__(256) void s4_build(const int2* __restrict__ ppair,
                                                const int* __restrict__ boffset,
                                                int* __restrict__ row_start,
                                                float* __restrict__ dis,
                                                int* __restrict__ csr) {
    __shared__ int h[BNODES];
    __shared__ int sc[BNODES];
    __shared__ int lcur[BNODES];
    int t = threadIdx.x;
    int b = blockIdx.x;
    int base = boffset[b];
    int cnt = boffset[b + 1] - base;
    int nodes0 = b << BSH;
    if (t < BNODES) h[t] = 0;
    __syncthreads();
    for (int j = t; j < cnt; j += 256)
        atomicAdd(&h[ppair[base + j].y - nodes0], 1);
    __syncthreads();
    if (t < BNODES) sc[t] = h[t];
    __syncthreads();
    for (int off = 1; off < BNODES; off <<= 1) {
        int u = (t < BNODES && t >= off) ? sc[t - off] : 0;
        __syncthreads();
        if (t < BNODES) sc[t] += u;
        __syncthreads();
    }
    if (t < BNODES) {
        int node = nodes0 + t;
        int excl = sc[t] - h[t];
        if (node < N_NODES) {
            row_start[node] = base + excl;
            dis[node] = rsqrtf((float)(h[t] + 1));
            lcur[t] = base + excl;
        }
    }
    __syncthreads();
    for (int j = t; j < cnt; j += 256) {
        int2 p = ppair[base + j];
        int slot = atomicAdd(&lcur[p.y - nodes0], 1);   // LDS atomic
        csr[slot] = p.x;
    }
}

__device__ __forceinline__ float4 fma4(float s, float4 w, float4 a) {
    a.x = fmaf(s, w.x, a.x);
    a.y = fmaf(s, w.y, a.y);
    a.z = fmaf(s, w.z, a.z);
    a.w = fmaf(s, w.w, a.w);
    return a;
}

// ---------------- hxs = bf16((x @ W1) * dis) ; 64x64 LDS-tiled, 4x4 per thread
__global__ __launch_bounds__(256) void k_xw(const float* __restrict__ x,
                                            const float* __restrict__ W1,
                                            const float* __restrict__ dis,
                                            unsigned short* __restrict__ hxs) {
    __shared__ float Ws[F_IN * HID];      // 32 KB, [k][c] (== W1 layout)
    __shared__ float Xs[XROWS * XPAD];    // 33 KB, [n][k] padded
    int t = threadIdx.x;
    int base = blockIdx.x * XROWS;

    for (int i = t; i < (F_IN * HID) / 4; i += 256)
        reinterpret_cast<float4*>(Ws)[i] = reinterpret_cast<const float4*>(W1)[i];

    for (int i = t; i < XROWS * (F_IN / 4); i += 256) {
        int n = i >> 5;           // 32 float4 per row
        int kq = i & 31;
        int gn = base + n;
        float4 v = make_float4(0.f, 0.f, 0.f, 0.f);
        if (gn < N_NODES)
            v = reinterpret_cast<const float4*>(x + (size_t)gn * F_IN)[kq];
        *reinterpret_cast<float4*>(&Xs[n * XPAD + kq * 4]) = v;
    }
    __syncthreads();

    int cg = (t & 15) * 4;        // col base: 16 groups x 4 cols
    int ng = (t >> 4) * 4;        // node base: 16 groups x 4 nodes
    float4 a0 = make_float4(0.f, 0.f, 0.f, 0.f);
    float4 a1 = a0, a2 = a0, a3 = a0;

#pragma unroll 4
    for (int k0 = 0; k0 < F_IN; k0 += 4) {
        float4 w0 = *reinterpret_cast<const float4*>(&Ws[(k0 + 0) * HID + cg]);
        float4 w1 = *reinterpret_cast<const float4*>(&Ws[(k0 + 1) * HID + cg]);
        float4 w2 = *reinterpret_cast<const float4*>(&Ws[(k0 + 2) * HID + cg]);
        float4 w3 = *reinterpret_cast<const float4*>(&Ws[(k0 + 3) * HID + cg]);
        float4 x0 = *reinterpret_cast<const float4*>(&Xs[(ng + 0) * XPAD + k0]);
        float4 x1 = *reinterpret_cast<const float4*>(&Xs[(ng + 1) * XPAD + k0]);
        float4 x2 = *reinterpret_cast<const float4*>(&Xs[(ng + 2) * XPAD + k0]);
        float4 x3 = *reinterpret_cast<const float4*>(&Xs[(ng + 3) * XPAD + k0]);
        a0 = fma4(x0.x, w0, a0); a0 = fma4(x0.y, w1, a0);
        a0 = fma4(x0.z, w2, a0); a0 = fma4(x0.w, w3, a0);
        a1 = fma4(x1.x, w0, a1); a1 = fma4(x1.y, w1, a1);
        a1 = fma4(x1.z, w2, a1); a1 = fma4(x1.w, w3, a1);
        a2 = fma4(x2.x, w0, a2); a2 = fma4(x2.y, w1, a2);
        a2 = fma4(x2.z, w2, a2); a2 = fma4(x2.w, w3, a2);
        a3 = fma4(x3.x, w0, a3); a3 = fma4(x3.y, w1, a3);
        a3 = fma4(x3.z, w2, a3); a3 = fma4(x3.w, w3, a3);
    }

    int n0 = base + ng;
    if (n0 + 0 < N_NODES) {
        float d = dis[n0 + 0];
        ushort4 o; o.x = f2bf(a0.x * d); o.y = f2bf(a0.y * d);
        o.z = f2bf(a0.z * d); o.w = f2bf(a0.w * d);
        *reinterpret_cast<ushort4*>(&hxs[(size_t)(n0 + 0) * HID + cg]) = o;
    }
    if (n0 + 1 < N_NODES) {
        float d = dis[n0 + 1];
        ushort4 o; o.x = f2bf(a1.x * d); o.y = f2bf(a1.y * d);
        o.z = f2bf(a1.z * d); o.w = f2bf(a1.w * d);
        *reinterpret_cast<ushort4*>(&hxs[(size_t)(n0 + 1) * HID + cg]) = o;
    }
    if (n0 + 2 < N_NODES) {
        float d = dis[n0 + 2];
        ushort4 o; o.x = f2bf(a2.x * d); o.y = f2bf(a2.y * d);
        o.z = f2bf(a2.z * d); o.w = f2bf(a2.w * d);
        *reinterpret_cast<ushort4*>(&hxs[(size_t)(n0 + 2) * HID + cg]) = o;
    }
    if (n0 + 3 < N_NODES) {
        float d = dis[n0 + 3];
        ushort4 o; o.x = f2bf(a3.x * d); o.y = f2bf(a3.y * d);
        o.z = f2bf(a3.z * d); o.w = f2bf(a3.w * d);
        *reinterpret_cast<ushort4*>(&hxs[(size_t)(n0 + 3) * HID + cg]) = o;
    }
}

// ---------------- fused: layer-1 aggregate + bias + relu + W2 + dis scale
// One wave per node. lane = k. h2s[n][c] = dis*( relu(agg*dis + b1) @ W2 )[c]
__global__ __launch_bounds__(256) void k_agg1f(const int* __restrict__ row_start,
                                               const int* __restrict__ csr,
                                               const float* __restrict__ dis,
                                               const unsigned short* __restrict__ hxs,
                                               const float* __restrict__ b1,
                                               const float* __restrict__ W2,
                                               float* __restrict__ h2s) {
    int lane = threadIdx.x & 63;
    int node = (blockIdx.x * blockDim.x + threadIdx.x) >> 6;
    if (node >= N_NODES) return;

    // per-lane W2 row (lane = k): 10 scalar loads, L1/L2-cached (2.5 KB total)
    const float* w2r = W2 + lane * NC;
    float w0 = w2r[0], w1 = w2r[1], w2 = w2r[2], w3 = w2r[3], w4 = w2r[4];
    float w5 = w2r[5], w6 = w2r[6], w7 = w2r[7], w8 = w2r[8], w9 = w2r[9];
    float bl = b1[lane];

    int beg = row_start[node], end = row_start[node + 1];
    float acc = bf2f(hxs[(size_t)node * HID + lane]);   // self message
    int j = beg;
    for (; j + 4 <= end; j += 4) {
        int s0 = csr[j], s1 = csr[j + 1], s2 = csr[j + 2], s3 = csr[j + 3];
        acc += bf2f(hxs[(size_t)s0 * HID + lane]);
        acc += bf2f(hxs[(size_t)s1 * HID + lane]);
        acc += bf2f(hxs[(size_t)s2 * HID + lane]);
        acc += bf2f(hxs[(size_t)s3 * HID + lane]);
    }
    for (; j < end; ++j)
        acc += bf2f(hxs[(size_t)csr[j] * HID + lane]);

    float v = acc * dis[node] + bl;       // h1 + b1
    v = v > 0.f ? v : 0.f;                // relu

    float s0 = v * w0, s1 = v * w1, s2 = v * w2, s3 = v * w3, s4 = v * w4;
    float s5 = v * w5, s6 = v * w6, s7 = v * w7, s8 = v * w8, s9 = v * w9;
#pragma unroll
    for (int off = 32; off >= 1; off >>= 1) {
        s0 += __shfl_xor(s0, off); s1 += __shfl_xor(s1, off);
        s2 += __shfl_xor(s2, off); s3 += __shfl_xor(s3, off);
        s4 += __shfl_xor(s4, off); s5 += __shfl_xor(s5, off);
        s6 += __shfl_xor(s6, off); s7 += __shfl_xor(s7, off);
        s8 += __shfl_xor(s8, off); s9 += __shfl_xor(s9, off);
    }
    float o = s0;
    o = (lane == 1) ? s1 : o; o = (lane == 2) ? s2 : o;
    o = (lane == 3) ? s3 : o; o = (lane == 4) ? s4 : o;
    o = (lane == 5) ? s5 : o; o = (lane == 6) ? s6 : o;
    o = (lane == 7) ? s7 : o; o = (lane == 8) ? s8 : o;
    o = (lane == 9) ? s9 : o;
    if (lane < NC)
        h2s[(size_t)node * NC + lane] = o * dis[node];
}

// ---------------- layer-2 aggregate + bias + log_softmax, fused
__global__ __launch_bounds__(256) void k_agg2f(const int* __restrict__ row_start,
                                               const int* __restrict__ csr,
                                               const float* __restrict__ dis,
                                               const float* __restrict__ h2s,
                                               const float* __restrict__ b2,
                                               float* __restrict__ out) {
    int c = threadIdx.x & 15;  // 16 lanes per node, 10 active
    int node = (blockIdx.x * blockDim.x + threadIdx.x) >> 4;
    if (node >= N_NODES) return;
    int beg = row_start[node], end = row_start[node + 1];
    float acc;
    if (c < NC) {
        acc = h2s[(size_t)node * NC + c];
        int j = beg;
        for (; j + 2 <= end; j += 2) {
            int s0 = csr[j], s1 = csr[j + 1];
            acc += h2s[(size_t)s0 * NC + c];
            acc += h2s[(size_t)s1 * NC + c];
        }
        for (; j < end; ++j)
            acc += h2s[(size_t)csr[j] * NC + c];
        acc = acc * dis[node] + b2[c];
    } else {
        acc = -1e30f;
    }
    float m = acc;
#pragma unroll
    for (int off = 8; off >= 1; off >>= 1)
        m = fmaxf(m, __shfl_xor(m, off, 16));
    float e = (c < NC) ? expf(acc - m) : 0.f;
    float ssum = e;
#pragma unroll
    for (int off = 8; off >= 1; off >>= 1)
        ssum += __shfl_xor(ssum, off, 16);
    float lse = m + logf(ssum);
    if (c < NC) out[(size_t)node * NC + c] = acc - lse;
}

static inline size_t align16(size_t v) { return (v + 15) & ~(size_t)15; }

extern "C" void kernel_launch(void* const* d_in, const int* in_sizes, int n_in,
                              void* d_out, int out_size, void* d_ws, size_t ws_size,
                              hipStream_t stream) {
    const float* x  = (const float*)d_in[0];
    const int*   ei = (const int*)d_in[1];    // [2, E] int32 (JAX x64 off)
    const float* W1 = (const float*)d_in[2];
    const float* b1 = (const float*)d_in[3];
    const float* W2 = (const float*)d_in[4];
    const float* b2 = (const float*)d_in[5];
    float* out = (float*)d_out;

    const int* src = ei;             // edge_index[0]
    const int* dst = ei + N_EDGES;   // edge_index[1]

    char* ws = (char*)d_ws;
    size_t off = 0;
    int* bcount = (int*)(ws + off);     off = align16(off + 4u * NB);
    int* boffset = (int*)(ws + off);    off = align16(off + 4u * (NB + 1));
    int* bcursor = (int*)(ws + off);    off = align16(off + 4u * NB);
    int* row_start = (int*)(ws + off);  off = align16(off + 4u * (N_NODES + 1));
    float* dis = (float*)(ws + off);    off = align16(off + 4u * N_NODES);
    int* csr = (int*)(ws + off);        off = align16(off + 4u * N_EDGES);           // 6.4 MB
    unsigned short* hxs = (unsigned short*)(ws + off);
    off = align16(off + 2u * (size_t)N_NODES * HID);                                 // 12.8 MB
    int2* ppair = (int2*)(ws + off);    off = align16(off + 8u * (size_t)N_EDGES);   // 12.8 MB
    float* h2s = (float*)(ws + off);    off = align16(off + 4u * (size_t)N_NODES * NC); // 4 MB

    hipMemsetAsync(bcount, 0, 4u * NB, stream);
    s1_bhist<<<PBLK, 256, 0, stream>>>(dst, bcount);
    s2_bscan<<<1, 1024, 0, stream>>>(bcount, boffset, bcursor, row_start);
    s3_part<<<PBLK, 256, 0, stream>>>(src, dst, bcursor, ppair);
    s4_build<<<NB, 256, 0, stream>>>(ppair, boffset, row_start, dis, csr);
    k_xw<<<(N_NODES + XROWS - 1) / XROWS, 256, 0, stream>>>(x, W1, dis, hxs);
    k_agg1f<<<(N_NODES * 64 + 255) / 256, 256, 0, stream>>>(row_start, csr, dis, hxs,
                                                            b1, W2, h2s);
    k_agg2f<<<(N_NODES * 16) / 256, 256, 0, stream>>>(row_start, csr, dis, h2s, b2, out);
}

// Round 8
// 182.345 us; speedup vs baseline: 4.1356x; 1.1998x over previous
//
#include <hip/hip_runtime.h>
#include <hip/hip_bf16.h>

#define N_NODES 100000
#define N_EDGES 1600000
#define F_IN 128
#define HID 64
#define NC 10

#define BSH 7
#define BNODES 128                       // nodes per bucket = 1<<BSH
#define NB 782                           // ceil(N_NODES / 128)
#define CAP 2560                         // padded bucket capacity (λ=2048, +11σ)
#define PBLK 256                         // partition blocks
#define TILE ((N_EDGES + PBLK - 1) / PBLK)  // 6250 edges per block

#define XROWS 64
#define XPAD 132                         // 528 B row: 16B-aligned, 2-way banks (free)

__device__ __forceinline__ unsigned short f2bf(float f) {
    unsigned u = __float_as_uint(f);
    u += 0x7FFFu + ((u >> 16) & 1u);     // round-to-nearest-even
    return (unsigned short)(u >> 16);
}
__device__ __forceinline__ float bf2f(unsigned short b) {
    return __uint_as_float(((unsigned)b) << 16);
}

// ---------------- init: bcursor[b] = b*CAP (replaces s1+s2+memset)
__global__ void k_init(int* __restrict__ bcursor) {
    int b = blockIdx.x * blockDim.x + threadIdx.x;
    if (b < NB) bcursor[b] = b * CAP;
}

// ---------------- s3: partition edges into padded bucket regions
// ppair entry = src | (local_dst << 20)   (src < 2^20, local_dst < 128)
__global__ __launch_bounds__(256) void s3_part(const int* __restrict__ src,
                                               const int* __restrict__ dst,
                                               int* __restrict__ bcursor,
                                               unsigned* __restrict__ ppair) {
    __shared__ int lh[NB];     // histogram, then running cursor
    __shared__ int lbase[NB];  // reserved base per bucket
    int t = threadIdx.x;
    for (int k = t; k < NB; k += 256) lh[k] = 0;
    __syncthreads();
    int b0 = blockIdx.x * TILE;
    int b1 = b0 + TILE < N_EDGES ? b0 + TILE : N_EDGES;
    for (int i = b0 + t; i < b1; i += 256)
        atomicAdd(&lh[dst[i] >> BSH], 1);
    __syncthreads();
    for (int k = t; k < NB; k += 256) {
        int c = lh[k];
        lbase[k] = c ? atomicAdd(&bcursor[k], c) : 0;  // coalesced, with return
    }
    __syncthreads();
    for (int k = t; k < NB; k += 256) lh[k] = lbase[k];
    __syncthreads();
    for (int i = b0 + t; i < b1; i += 256) {
        int d = dst[i];
        int slot = atomicAdd(&lh[d >> BSH], 1);        // LDS atomic (fast)
        ppair[slot] = (unsigned)src[i] | ((unsigned)(d & (BNODES - 1)) << 20);
    }
}

// ---------------- s4: per-bucket CSR finalize (row_info, dis, padded csr)
__global__ __launch_bounds__(256) void s4_build(const unsigned* __restrict__ ppair,
                                                const int* __restrict__ bcursor,
                                                int2* __restrict__ row_info,
                                                float* __restrict__ dis,
                                                int* __restrict__ csr) {
    __shared__ int h[BNODES];
    __shared__ int sc[BNODES];
    __shared__ int lcur[BNODES];
    int t = threadIdx.x;
    int b = blockIdx.x;
    int base = b * CAP;
    int cnt = bcursor[b] - base;
    int nodes0 = b << BSH;
    if (t < BNODES) h[t] = 0;
    __syncthreads();
    for (int j = t; j < cnt; j += 256)
        atomicAdd(&h[ppair[base + j] >> 20], 1);
    __syncthreads();
    if (t < BNODES) sc[t] = h[t];
    __syncthreads();
    for (int off = 1; off < BNODES; off <<= 1) {
        int u = (t < BNODES && t >= off) ? sc[t - off] : 0;
        __syncthreads();
        if (t < BNODES) sc[t] += u;
        __syncthreads();
    }
    if (t < BNODES) {
        int node = nodes0 + t;
        int excl = sc[t] - h[t];
        if (node < N_NODES) {
            row_info[node] = make_int2(base + excl, h[t]);
            dis[node] = rsqrtf((float)(h[t] + 1));
            lcur[t] = base + excl;
        }
    }
    __syncthreads();
    for (int j = t; j < cnt; j += 256) {
        unsigned p = ppair[base + j];
        int slot = atomicAdd(&lcur[p >> 20], 1);        // LDS atomic
        csr[slot] = (int)(p & 0xFFFFFu);
    }
}

__device__ __forceinline__ float4 fma4(float s, float4 w, float4 a) {
    a.x = fmaf(s, w.x, a.x);
    a.y = fmaf(s, w.y, a.y);
    a.z = fmaf(s, w.z, a.z);
    a.w = fmaf(s, w.w, a.w);
    return a;
}

// ---------------- hxs = bf16((x @ W1) * dis) ; 64x64 LDS-tiled, 4x4 per thread
__global__ __launch_bounds__(256) void k_xw(const float* __restrict__ x,
                                            const float* __restrict__ W1,
                                            const float* __restrict__ dis,
                                            unsigned short* __restrict__ hxs) {
    __shared__ float Ws[F_IN * HID];      // 32 KB, [k][c] (== W1 layout)
    __shared__ float Xs[XROWS * XPAD];    // 33 KB, [n][k] padded
    int t = threadIdx.x;
    int base = blockIdx.x * XROWS;

    for (int i = t; i < (F_IN * HID) / 4; i += 256)
        reinterpret_cast<float4*>(Ws)[i] = reinterpret_cast<const float4*>(W1)[i];

    for (int i = t; i < XROWS * (F_IN / 4); i += 256) {
        int n = i >> 5;           // 32 float4 per row
        int kq = i & 31;
        int gn = base + n;
        float4 v = make_float4(0.f, 0.f, 0.f, 0.f);
        if (gn < N_NODES)
            v = reinterpret_cast<const float4*>(x + (size_t)gn * F_IN)[kq];
        *reinterpret_cast<float4*>(&Xs[n * XPAD + kq * 4]) = v;
    }
    __syncthreads();

    int cg = (t & 15) * 4;        // col base: 16 groups x 4 cols
    int ng = (t >> 4) * 4;        // node base: 16 groups x 4 nodes
    float4 a0 = make_float4(0.f, 0.f, 0.f, 0.f);
    float4 a1 = a0, a2 = a0, a3 = a0;

#pragma unroll 4
    for (int k0 = 0; k0 < F_IN; k0 += 4) {
        float4 w0 = *reinterpret_cast<const float4*>(&Ws[(k0 + 0) * HID + cg]);
        float4 w1 = *reinterpret_cast<const float4*>(&Ws[(k0 + 1) * HID + cg]);
        float4 w2 = *reinterpret_cast<const float4*>(&Ws[(k0 + 2) * HID + cg]);
        float4 w3 = *reinterpret_cast<const float4*>(&Ws[(k0 + 3) * HID + cg]);
        float4 x0 = *reinterpret_cast<const float4*>(&Xs[(ng + 0) * XPAD + k0]);
        float4 x1 = *reinterpret_cast<const float4*>(&Xs[(ng + 1) * XPAD + k0]);
        float4 x2 = *reinterpret_cast<const float4*>(&Xs[(ng + 2) * XPAD + k0]);
        float4 x3 = *reinterpret_cast<const float4*>(&Xs[(ng + 3) * XPAD + k0]);
        a0 = fma4(x0.x, w0, a0); a0 = fma4(x0.y, w1, a0);
        a0 = fma4(x0.z, w2, a0); a0 = fma4(x0.w, w3, a0);
        a1 = fma4(x1.x, w0, a1); a1 = fma4(x1.y, w1, a1);
        a1 = fma4(x1.z, w2, a1); a1 = fma4(x1.w, w3, a1);
        a2 = fma4(x2.x, w0, a2); a2 = fma4(x2.y, w1, a2);
        a2 = fma4(x2.z, w2, a2); a2 = fma4(x2.w, w3, a2);
        a3 = fma4(x3.x, w0, a3); a3 = fma4(x3.y, w1, a3);
        a3 = fma4(x3.z, w2, a3); a3 = fma4(x3.w, w3, a3);
    }

    int n0 = base + ng;
    if (n0 + 0 < N_NODES) {
        float d = dis[n0 + 0];
        ushort4 o; o.x = f2bf(a0.x * d); o.y = f2bf(a0.y * d);
        o.z = f2bf(a0.z * d); o.w = f2bf(a0.w * d);
        *reinterpret_cast<ushort4*>(&hxs[(size_t)(n0 + 0) * HID + cg]) = o;
    }
    if (n0 + 1 < N_NODES) {
        float d = dis[n0 + 1];
        ushort4 o; o.x = f2bf(a1.x * d); o.y = f2bf(a1.y * d);
        o.z = f2bf(a1.z * d); o.w = f2bf(a1.w * d);
        *reinterpret_cast<ushort4*>(&hxs[(size_t)(n0 + 1) * HID + cg]) = o;
    }
    if (n0 + 2 < N_NODES) {
        float d = dis[n0 + 2];
        ushort4 o; o.x = f2bf(a2.x * d); o.y = f2bf(a2.y * d);
        o.z = f2bf(a2.z * d); o.w = f2bf(a2.w * d);
        *reinterpret_cast<ushort4*>(&hxs[(size_t)(n0 + 2) * HID + cg]) = o;
    }
    if (n0 + 3 < N_NODES) {
        float d = dis[n0 + 3];
        ushort4 o; o.x = f2bf(a3.x * d); o.y = f2bf(a3.y * d);
        o.z = f2bf(a3.z * d); o.w = f2bf(a3.w * d);
        *reinterpret_cast<ushort4*>(&hxs[(size_t)(n0 + 3) * HID + cg]) = o;
    }
}

// ---------------- fused layer-1 aggregate + bias + relu + W2 + scale -> bf16 h2s
// One wave per node; lane&31 = uint col-pair; lane>>5 = edge parity.
__global__ __launch_bounds__(256) void k_agg1f(const int2* __restrict__ row_info,
                                               const float* __restrict__ dis,
                                               const unsigned* __restrict__ hxsu,
                                               const int* __restrict__ csr,
                                               const float* __restrict__ b1,
                                               const float* __restrict__ W2,
                                               unsigned short* __restrict__ h2s) {
    int lane = threadIdx.x & 63;
    int node = (blockIdx.x * blockDim.x + threadIdx.x) >> 6;
    if (node >= N_NODES) return;
    int col2 = lane & 31;
    int half = lane >> 5;

    // hoisted per-lane constants (L1-cached, issue early)
    float bl0 = b1[2 * col2], bl1 = b1[2 * col2 + 1];
    const float* w0p = W2 + (2 * col2) * NC;
    const float* w1p = W2 + (2 * col2 + 1) * NC;

    int2 ri = row_info[node];
    int beg = ri.x, m = ri.y;
    float ax = 0.f, ay = 0.f;
    int j = 0;
    for (; j + 8 <= m; j += 8) {                  // 8 edges per iter, 4 per half
        int i0 = beg + j + half;
        int e0 = csr[i0],     e1 = csr[i0 + 2];
        int e2 = csr[i0 + 4], e3 = csr[i0 + 6];
        unsigned u0 = hxsu[(size_t)e0 * 32 + col2];
        unsigned u1 = hxsu[(size_t)e1 * 32 + col2];
        unsigned u2 = hxsu[(size_t)e2 * 32 + col2];
        unsigned u3 = hxsu[(size_t)e3 * 32 + col2];
        ax += __uint_as_float(u0 << 16); ay += __uint_as_float(u0 & 0xffff0000u);
        ax += __uint_as_float(u1 << 16); ay += __uint_as_float(u1 & 0xffff0000u);
        ax += __uint_as_float(u2 << 16); ay += __uint_as_float(u2 & 0xffff0000u);
        ax += __uint_as_float(u3 << 16); ay += __uint_as_float(u3 & 0xffff0000u);
    }
    for (; j < m; j += 2) {                       // tail, 2 at a time w/ guard
        int idx = j + half;
        bool ok = idx < m;
        int e = csr[beg + (ok ? idx : 0)];
        unsigned u = hxsu[(size_t)e * 32 + col2];
        if (ok) {
            ax += __uint_as_float(u << 16);
            ay += __uint_as_float(u & 0xffff0000u);
        }
    }
    // merge edge-parity halves (all 64 lanes end consistent)
    ax += __shfl_xor(ax, 32);
    ay += __shfl_xor(ay, 32);
    // self message
    unsigned us = hxsu[(size_t)node * 32 + col2];
    ax += __uint_as_float(us << 16);
    ay += __uint_as_float(us & 0xffff0000u);

    float dn = dis[node];
    float vx = ax * dn + bl0; vx = vx > 0.f ? vx : 0.f;
    float vy = ay * dn + bl1; vy = vy > 0.f ? vy : 0.f;

    float s0 = vx * w0p[0] + vy * w1p[0];
    float s1 = vx * w0p[1] + vy * w1p[1];
    float s2 = vx * w0p[2] + vy * w1p[2];
    float s3 = vx * w0p[3] + vy * w1p[3];
    float s4 = vx * w0p[4] + vy * w1p[4];
    float s5 = vx * w0p[5] + vy * w1p[5];
    float s6 = vx * w0p[6] + vy * w1p[6];
    float s7 = vx * w0p[7] + vy * w1p[7];
    float s8 = vx * w0p[8] + vy * w1p[8];
    float s9 = vx * w0p[9] + vy * w1p[9];
#pragma unroll
    for (int off = 16; off >= 1; off >>= 1) {     // 5 rounds over 32-lane groups
        s0 += __shfl_xor(s0, off); s1 += __shfl_xor(s1, off);
        s2 += __shfl_xor(s2, off); s3 += __shfl_xor(s3, off);
        s4 += __shfl_xor(s4, off); s5 += __shfl_xor(s5, off);
        s6 += __shfl_xor(s6, off); s7 += __shfl_xor(s7, off);
        s8 += __shfl_xor(s8, off); s9 += __shfl_xor(s9, off);
    }
    float o = s0;
    o = (lane == 1) ? s1 : o; o = (lane == 2) ? s2 : o;
    o = (lane == 3) ? s3 : o; o = (lane == 4) ? s4 : o;
    o = (lane == 5) ? s5 : o; o = (lane == 6) ? s6 : o;
    o = (lane == 7) ? s7 : o; o = (lane == 8) ? s8 : o;
    o = (lane == 9) ? s9 : o;
    if (lane < NC)
        h2s[(size_t)node * NC + lane] = f2bf(o * dn);
}

// ---------------- layer-2 aggregate + bias + log_softmax (bf16 h2s)
__global__ __launch_bounds__(256) void k_agg2f(const int2* __restrict__ row_info,
                                               const float* __restrict__ dis,
                                               const unsigned short* __restrict__ h2s,
                                               const int* __restrict__ csr,
                                               const float* __restrict__ b2,
                                               float* __restrict__ out) {
    int c = threadIdx.x & 15;  // 16 lanes per node, 10 active
    int node = (blockIdx.x * blockDim.x + threadIdx.x) >> 4;
    if (node >= N_NODES) return;
    int2 ri = row_info[node];
    int beg = ri.x, m = ri.y;
    float acc;
    if (c < NC) {
        acc = bf2f(h2s[(size_t)node * NC + c]);
        int j = 0;
        for (; j + 2 <= m; j += 2) {
            int s0 = csr[beg + j], s1 = csr[beg + j + 1];
            acc += bf2f(h2s[(size_t)s0 * NC + c]);
            acc += bf2f(h2s[(size_t)s1 * NC + c]);
        }
        for (; j < m; ++j)
            acc += bf2f(h2s[(size_t)csr[beg + j] * NC + c]);
        acc = acc * dis[node] + b2[c];
    } else {
        acc = -1e30f;
    }
    float mx = acc;
#pragma unroll
    for (int off = 8; off >= 1; off >>= 1)
        mx = fmaxf(mx, __shfl_xor(mx, off, 16));
    float e = (c < NC) ? expf(acc - mx) : 0.f;
    float ssum = e;
#pragma unroll
    for (int off = 8; off >= 1; off >>= 1)
        ssum += __shfl_xor(ssum, off, 16);
    float lse = mx + logf(ssum);
    if (c < NC) out[(size_t)node * NC + c] = acc - lse;
}

static inline size_t align16(size_t v) { return (v + 15) & ~(size_t)15; }

extern "C" void kernel_launch(void* const* d_in, const int* in_sizes, int n_in,
                              void* d_out, int out_size, void* d_ws, size_t ws_size,
                              hipStream_t stream) {
    const float* x  = (const float*)d_in[0];
    const int*   ei = (const int*)d_in[1];    // [2, E] int32 (JAX x64 off)
    const float* W1 = (const float*)d_in[2];
    const float* b1 = (const float*)d_in[3];
    const float* W2 = (const float*)d_in[4];
    const float* b2 = (const float*)d_in[5];
    float* out = (float*)d_out;

    const int* src = ei;             // edge_index[0]
    const int* dst = ei + N_EDGES;   // edge_index[1]

    char* ws = (char*)d_ws;
    size_t off = 0;
    int* bcursor = (int*)(ws + off);     off = align16(off + 4u * NB);
    int2* row_info = (int2*)(ws + off);  off = align16(off + 8u * (size_t)N_NODES);   // 0.8 MB
    float* dis = (float*)(ws + off);     off = align16(off + 4u * N_NODES);           // 0.4 MB
    int* csr = (int*)(ws + off);         off = align16(off + 4u * (size_t)NB * CAP);  // 8.0 MB
    unsigned* ppair = (unsigned*)(ws + off);
    off = align16(off + 4u * (size_t)NB * CAP);                                       // 8.0 MB
    unsigned short* hxs = (unsigned short*)(ws + off);
    off = align16(off + 2u * (size_t)N_NODES * HID);                                  // 12.8 MB
    unsigned short* h2s = (unsigned short*)(ws + off);
    off = align16(off + 2u * (size_t)N_NODES * NC);                                   // 2.0 MB

    k_init<<<(NB + 255) / 256, 256, 0, stream>>>(bcursor);
    s3_part<<<PBLK, 256, 0, stream>>>(src, dst, bcursor, ppair);
    s4_build<<<NB, 256, 0, stream>>>(ppair, bcursor, row_info, dis, csr);
    k_xw<<<(N_NODES + XROWS - 1) / XROWS, 256, 0, stream>>>(x, W1, dis, hxs);
    k_agg1f<<<(N_NODES * 64 + 255) / 256, 256, 0, stream>>>(
        row_info, dis, (const unsigned*)hxs, csr, b1, W2, h2s);
    k_agg2f<<<(N_NODES * 16 + 255) / 256, 256, 0, stream>>>(
        row_info, dis, h2s, csr, b2, out);
}

// Round 9
// 175.935 us; speedup vs baseline: 4.2863x; 1.0364x over previous
//
#include <hip/hip_runtime.h>
#include <hip/hip_bf16.h>

#define N_NODES 100000
#define N_EDGES 1600000
#define F_IN 128
#define HID 64
#define NC 10

#define BSH 7
#define BNODES 128                       // nodes per bucket = 1<<BSH
#define NB 782                           // ceil(N_NODES / 128)
#define CAP 2560                         // padded bucket capacity (λ=2048, +11σ)
#define PBLK 256                         // partition blocks
#define TILE ((N_EDGES + PBLK - 1) / PBLK)  // 6250 edges per block

#define XROWS 64
#define XPAD 132                         // 528 B row: 16B-aligned, 2-way banks (free)

__device__ __forceinline__ unsigned short f2bf(float f) {
    unsigned u = __float_as_uint(f);
    u += 0x7FFFu + ((u >> 16) & 1u);     // round-to-nearest-even
    return (unsigned short)(u >> 16);
}
__device__ __forceinline__ float bf2f(unsigned short b) {
    return __uint_as_float(((unsigned)b) << 16);
}

// ---------------- init: bcursor[b] = b*CAP (replaces s1+s2+memset)
__global__ void k_init(int* __restrict__ bcursor) {
    int b = blockIdx.x * blockDim.x + threadIdx.x;
    if (b < NB) bcursor[b] = b * CAP;
}

// ---------------- s3: partition edges into padded bucket regions
// ppair entry = src | (local_dst << 20)   (src < 2^20, local_dst < 128)
__global__ __launch_bounds__(256) void s3_part(const int* __restrict__ src,
                                               const int* __restrict__ dst,
                                               int* __restrict__ bcursor,
                                               unsigned* __restrict__ ppair) {
    __shared__ int lh[NB];     // histogram, then running cursor
    int t = threadIdx.x;
    for (int k = t; k < NB; k += 256) lh[k] = 0;
    __syncthreads();
    int b0 = blockIdx.x * TILE;
    int b1 = b0 + TILE < N_EDGES ? b0 + TILE : N_EDGES;
    for (int i = b0 + t; i < b1; i += 256)
        atomicAdd(&lh[dst[i] >> BSH], 1);
    __syncthreads();
    // reserve contiguous run per bucket; overwrite count with base in-place
    for (int k = t; k < NB; k += 256) {
        int c = lh[k];
        lh[k] = c ? atomicAdd(&bcursor[k], c) : 0;   // coalesced, with return
    }
    __syncthreads();
    for (int i = b0 + t; i < b1; i += 256) {
        int d = dst[i];
        int slot = atomicAdd(&lh[d >> BSH], 1);      // LDS atomic (fast)
        ppair[slot] = (unsigned)src[i] | ((unsigned)(d & (BNODES - 1)) << 20);
    }
}

// ---------------- s4: per-bucket CSR finalize (row_info, dis, padded csr)
__global__ __launch_bounds__(256) void s4_build(const unsigned* __restrict__ ppair,
                                                const int* __restrict__ bcursor,
                                                int2* __restrict__ row_info,
                                                float* __restrict__ dis,
                                                int* __restrict__ csr) {
    __shared__ int h[BNODES];
    __shared__ int sc[BNODES];
    __shared__ int lcur[BNODES];
    int t = threadIdx.x;
    int b = blockIdx.x;
    int base = b * CAP;
    int cnt = bcursor[b] - base;
    int nodes0 = b << BSH;
    if (t < BNODES) h[t] = 0;
    __syncthreads();
    for (int j = t; j < cnt; j += 256)
        atomicAdd(&h[ppair[base + j] >> 20], 1);
    __syncthreads();
    if (t < BNODES) sc[t] = h[t];
    __syncthreads();
    for (int off = 1; off < BNODES; off <<= 1) {
        int u = (t < BNODES && t >= off) ? sc[t - off] : 0;
        __syncthreads();
        if (t < BNODES) sc[t] += u;
        __syncthreads();
    }
    if (t < BNODES) {
        int node = nodes0 + t;
        int excl = sc[t] - h[t];
        if (node < N_NODES) {
            row_info[node] = make_int2(base + excl, h[t]);
            dis[node] = rsqrtf((float)(h[t] + 1));
            lcur[t] = base + excl;
        }
    }
    __syncthreads();
    for (int j = t; j < cnt; j += 256) {
        unsigned p = ppair[base + j];
        int slot = atomicAdd(&lcur[p >> 20], 1);        // LDS atomic
        csr[slot] = (int)(p & 0xFFFFFu);
    }
}

__device__ __forceinline__ float4 fma4(float s, float4 w, float4 a) {
    a.x = fmaf(s, w.x, a.x);
    a.y = fmaf(s, w.y, a.y);
    a.z = fmaf(s, w.z, a.z);
    a.w = fmaf(s, w.w, a.w);
    return a;
}

// ---------------- hxs = bf16((x @ W1) * dis) ; 64x64 LDS-tiled, 4x4 per thread
__global__ __launch_bounds__(256) void k_xw(const float* __restrict__ x,
                                            const float* __restrict__ W1,
                                            const float* __restrict__ dis,
                                            unsigned short* __restrict__ hxs) {
    __shared__ float Ws[F_IN * HID];      // 32 KB, [k][c] (== W1 layout)
    __shared__ float Xs[XROWS * XPAD];    // 33 KB, [n][k] padded
    int t = threadIdx.x;
    int base = blockIdx.x * XROWS;

    for (int i = t; i < (F_IN * HID) / 4; i += 256)
        reinterpret_cast<float4*>(Ws)[i] = reinterpret_cast<const float4*>(W1)[i];

    for (int i = t; i < XROWS * (F_IN / 4); i += 256) {
        int n = i >> 5;           // 32 float4 per row
        int kq = i & 31;
        int gn = base + n;
        float4 v = make_float4(0.f, 0.f, 0.f, 0.f);
        if (gn < N_NODES)
            v = reinterpret_cast<const float4*>(x + (size_t)gn * F_IN)[kq];
        *reinterpret_cast<float4*>(&Xs[n * XPAD + kq * 4]) = v;
    }
    __syncthreads();

    int cg = (t & 15) * 4;        // col base: 16 groups x 4 cols
    int ng = (t >> 4) * 4;        // node base: 16 groups x 4 nodes
    float4 a0 = make_float4(0.f, 0.f, 0.f, 0.f);
    float4 a1 = a0, a2 = a0, a3 = a0;

#pragma unroll 4
    for (int k0 = 0; k0 < F_IN; k0 += 4) {
        float4 w0 = *reinterpret_cast<const float4*>(&Ws[(k0 + 0) * HID + cg]);
        float4 w1 = *reinterpret_cast<const float4*>(&Ws[(k0 + 1) * HID + cg]);
        float4 w2 = *reinterpret_cast<const float4*>(&Ws[(k0 + 2) * HID + cg]);
        float4 w3 = *reinterpret_cast<const float4*>(&Ws[(k0 + 3) * HID + cg]);
        float4 x0 = *reinterpret_cast<const float4*>(&Xs[(ng + 0) * XPAD + k0]);
        float4 x1 = *reinterpret_cast<const float4*>(&Xs[(ng + 1) * XPAD + k0]);
        float4 x2 = *reinterpret_cast<const float4*>(&Xs[(ng + 2) * XPAD + k0]);
        float4 x3 = *reinterpret_cast<const float4*>(&Xs[(ng + 3) * XPAD + k0]);
        a0 = fma4(x0.x, w0, a0); a0 = fma4(x0.y, w1, a0);
        a0 = fma4(x0.z, w2, a0); a0 = fma4(x0.w, w3, a0);
        a1 = fma4(x1.x, w0, a1); a1 = fma4(x1.y, w1, a1);
        a1 = fma4(x1.z, w2, a1); a1 = fma4(x1.w, w3, a1);
        a2 = fma4(x2.x, w0, a2); a2 = fma4(x2.y, w1, a2);
        a2 = fma4(x2.z, w2, a2); a2 = fma4(x2.w, w3, a2);
        a3 = fma4(x3.x, w0, a3); a3 = fma4(x3.y, w1, a3);
        a3 = fma4(x3.z, w2, a3); a3 = fma4(x3.w, w3, a3);
    }

    int n0 = base + ng;
    if (n0 + 0 < N_NODES) {
        float d = dis[n0 + 0];
        ushort4 o; o.x = f2bf(a0.x * d); o.y = f2bf(a0.y * d);
        o.z = f2bf(a0.z * d); o.w = f2bf(a0.w * d);
        *reinterpret_cast<ushort4*>(&hxs[(size_t)(n0 + 0) * HID + cg]) = o;
    }
    if (n0 + 1 < N_NODES) {
        float d = dis[n0 + 1];
        ushort4 o; o.x = f2bf(a1.x * d); o.y = f2bf(a1.y * d);
        o.z = f2bf(a1.z * d); o.w = f2bf(a1.w * d);
        *reinterpret_cast<ushort4*>(&hxs[(size_t)(n0 + 1) * HID + cg]) = o;
    }
    if (n0 + 2 < N_NODES) {
        float d = dis[n0 + 2];
        ushort4 o; o.x = f2bf(a2.x * d); o.y = f2bf(a2.y * d);
        o.z = f2bf(a2.z * d); o.w = f2bf(a2.w * d);
        *reinterpret_cast<ushort4*>(&hxs[(size_t)(n0 + 2) * HID + cg]) = o;
    }
    if (n0 + 3 < N_NODES) {
        float d = dis[n0 + 3];
        ushort4 o; o.x = f2bf(a3.x * d); o.y = f2bf(a3.y * d);
        o.z = f2bf(a3.z * d); o.w = f2bf(a3.w * d);
        *reinterpret_cast<ushort4*>(&hxs[(size_t)(n0 + 3) * HID + cg]) = o;
    }
}

// ---------------- fused layer-1 aggregate + bias + relu + W2 + scale -> bf16 h2s
// One wave per node; lane&31 = uint col-pair; lane>>5 = edge parity.
// Tail handled by ONE predicated 8-edge round (no serial 2-edge tail).
__global__ __launch_bounds__(256) void k_agg1f(const int2* __restrict__ row_info,
                                               const float* __restrict__ dis,
                                               const unsigned* __restrict__ hxsu,
                                               const int* __restrict__ csr,
                                               const float* __restrict__ b1,
                                               const float* __restrict__ W2,
                                               unsigned short* __restrict__ h2s) {
    int lane = threadIdx.x & 63;
    int node = (blockIdx.x * blockDim.x + threadIdx.x) >> 6;
    if (node >= N_NODES) return;
    int col2 = lane & 31;
    int half = lane >> 5;

    // hoisted per-lane constants (L1-cached, issue early)
    float bl0 = b1[2 * col2], bl1 = b1[2 * col2 + 1];
    const float* w0p = W2 + (2 * col2) * NC;
    const float* w1p = W2 + (2 * col2 + 1) * NC;

    int2 ri = row_info[node];
    int beg = ri.x, m = ri.y;
    float ax = 0.f, ay = 0.f;
    int mmain = m & ~7;
    int j = 0;
    for (; j < mmain; j += 8) {                   // 8 edges per iter, 4 per half
        int i0 = beg + j + half;
        int e0 = csr[i0],     e1 = csr[i0 + 2];
        int e2 = csr[i0 + 4], e3 = csr[i0 + 6];
        unsigned u0 = hxsu[(size_t)e0 * 32 + col2];
        unsigned u1 = hxsu[(size_t)e1 * 32 + col2];
        unsigned u2 = hxsu[(size_t)e2 * 32 + col2];
        unsigned u3 = hxsu[(size_t)e3 * 32 + col2];
        ax += __uint_as_float(u0 << 16); ay += __uint_as_float(u0 & 0xffff0000u);
        ax += __uint_as_float(u1 << 16); ay += __uint_as_float(u1 & 0xffff0000u);
        ax += __uint_as_float(u2 << 16); ay += __uint_as_float(u2 & 0xffff0000u);
        ax += __uint_as_float(u3 << 16); ay += __uint_as_float(u3 & 0xffff0000u);
    }
    if (j < m) {                                  // ONE predicated 8-edge round
        int i0 = j + half;                        // logical indices i0, i0+2, i0+4, i0+6
        bool v0 = i0 < m, v1 = i0 + 2 < m, v2 = i0 + 4 < m, v3 = i0 + 6 < m;
        int e0 = csr[beg + (v0 ? i0     : 0)];
        int e1 = csr[beg + (v1 ? i0 + 2 : 0)];
        int e2 = csr[beg + (v2 ? i0 + 4 : 0)];
        int e3 = csr[beg + (v3 ? i0 + 6 : 0)];
        unsigned u0 = hxsu[(size_t)e0 * 32 + col2];
        unsigned u1 = hxsu[(size_t)e1 * 32 + col2];
        unsigned u2 = hxsu[(size_t)e2 * 32 + col2];
        unsigned u3 = hxsu[(size_t)e3 * 32 + col2];
        ax += v0 ? __uint_as_float(u0 << 16) : 0.f;
        ay += v0 ? __uint_as_float(u0 & 0xffff0000u) : 0.f;
        ax += v1 ? __uint_as_float(u1 << 16) : 0.f;
        ay += v1 ? __uint_as_float(u1 & 0xffff0000u) : 0.f;
        ax += v2 ? __uint_as_float(u2 << 16) : 0.f;
        ay += v2 ? __uint_as_float(u2 & 0xffff0000u) : 0.f;
        ax += v3 ? __uint_as_float(u3 << 16) : 0.f;
        ay += v3 ? __uint_as_float(u3 & 0xffff0000u) : 0.f;
    }
    // merge edge-parity halves (all 64 lanes end consistent)
    ax += __shfl_xor(ax, 32);
    ay += __shfl_xor(ay, 32);
    // self message
    unsigned us = hxsu[(size_t)node * 32 + col2];
    ax += __uint_as_float(us << 16);
    ay += __uint_as_float(us & 0xffff0000u);

    float dn = dis[node];
    float vx = ax * dn + bl0; vx = vx > 0.f ? vx : 0.f;
    float vy = ay * dn + bl1; vy = vy > 0.f ? vy : 0.f;

    float s0 = vx * w0p[0] + vy * w1p[0];
    float s1 = vx * w0p[1] + vy * w1p[1];
    float s2 = vx * w0p[2] + vy * w1p[2];
    float s3 = vx * w0p[3] + vy * w1p[3];
    float s4 = vx * w0p[4] + vy * w1p[4];
    float s5 = vx * w0p[5] + vy * w1p[5];
    float s6 = vx * w0p[6] + vy * w1p[6];
    float s7 = vx * w0p[7] + vy * w1p[7];
    float s8 = vx * w0p[8] + vy * w1p[8];
    float s9 = vx * w0p[9] + vy * w1p[9];
#pragma unroll
    for (int off = 16; off >= 1; off >>= 1) {     // 5 rounds over 32-lane groups
        s0 += __shfl_xor(s0, off); s1 += __shfl_xor(s1, off);
        s2 += __shfl_xor(s2, off); s3 += __shfl_xor(s3, off);
        s4 += __shfl_xor(s4, off); s5 += __shfl_xor(s5, off);
        s6 += __shfl_xor(s6, off); s7 += __shfl_xor(s7, off);
        s8 += __shfl_xor(s8, off); s9 += __shfl_xor(s9, off);
    }
    float o = s0;
    o = (lane == 1) ? s1 : o; o = (lane == 2) ? s2 : o;
    o = (lane == 3) ? s3 : o; o = (lane == 4) ? s4 : o;
    o = (lane == 5) ? s5 : o; o = (lane == 6) ? s6 : o;
    o = (lane == 7) ? s7 : o; o = (lane == 8) ? s8 : o;
    o = (lane == 9) ? s9 : o;
    if (lane < NC)
        h2s[(size_t)node * NC + lane] = f2bf(o * dn);
}

// ---------------- layer-2 aggregate + bias + log_softmax (bf16 h2s)
__global__ __launch_bounds__(256) void k_agg2f(const int2* __restrict__ row_info,
                                               const float* __restrict__ dis,
                                               const unsigned short* __restrict__ h2s,
                                               const int* __restrict__ csr,
                                               const float* __restrict__ b2,
                                               float* __restrict__ out) {
    int c = threadIdx.x & 15;  // 16 lanes per node, 10 active
    int node = (blockIdx.x * blockDim.x + threadIdx.x) >> 4;
    if (node >= N_NODES) return;
    int2 ri = row_info[node];
    int beg = ri.x, m = ri.y;
    float acc;
    if (c < NC) {
        acc = bf2f(h2s[(size_t)node * NC + c]);
        int j = 0;
        for (; j + 2 <= m; j += 2) {
            int s0 = csr[beg + j], s1 = csr[beg + j + 1];
            acc += bf2f(h2s[(size_t)s0 * NC + c]);
            acc += bf2f(h2s[(size_t)s1 * NC + c]);
        }
        for (; j < m; ++j)
            acc += bf2f(h2s[(size_t)csr[beg + j] * NC + c]);
        acc = acc * dis[node] + b2[c];
    } else {
        acc = -1e30f;
    }
    float mx = acc;
#pragma unroll
    for (int off = 8; off >= 1; off >>= 1)
        mx = fmaxf(mx, __shfl_xor(mx, off, 16));
    float e = (c < NC) ? expf(acc - mx) : 0.f;
    float ssum = e;
#pragma unroll
    for (int off = 8; off >= 1; off >>= 1)
        ssum += __shfl_xor(ssum, off, 16);
    float lse = mx + logf(ssum);
    if (c < NC) out[(size_t)node * NC + c] = acc - lse;
}

static inline size_t align16(size_t v) { return (v + 15) & ~(size_t)15; }

extern "C" void kernel_launch(void* const* d_in, const int* in_sizes, int n_in,
                              void* d_out, int out_size, void* d_ws, size_t ws_size,
                              hipStream_t stream) {
    const float* x  = (const float*)d_in[0];
    const int*   ei = (const int*)d_in[1];    // [2, E] int32 (JAX x64 off)
    const float* W1 = (const float*)d_in[2];
    const float* b1 = (const float*)d_in[3];
    const float* W2 = (const float*)d_in[4];
    const float* b2 = (const float*)d_in[5];
    float* out = (float*)d_out;

    const int* src = ei;             // edge_index[0]
    const int* dst = ei + N_EDGES;   // edge_index[1]

    char* ws = (char*)d_ws;
    size_t off = 0;
    int* bcursor = (int*)(ws + off);     off = align16(off + 4u * NB);
    int2* row_info = (int2*)(ws + off);  off = align16(off + 8u * (size_t)N_NODES);   // 0.8 MB
    float* dis = (float*)(ws + off);     off = align16(off + 4u * N_NODES);           // 0.4 MB
    int* csr = (int*)(ws + off);         off = align16(off + 4u * (size_t)NB * CAP);  // 8.0 MB
    unsigned* ppair = (unsigned*)(ws + off);
    off = align16(off + 4u * (size_t)NB * CAP);                                       // 8.0 MB
    unsigned short* hxs = (unsigned short*)(ws + off);
    off = align16(off + 2u * (size_t)N_NODES * HID);                                  // 12.8 MB
    unsigned short* h2s = (unsigned short*)(ws + off);
    off = align16(off + 2u * (size_t)N_NODES * NC);                                   // 2.0 MB

    k_init<<<(NB + 255) / 256, 256, 0, stream>>>(bcursor);
    s3_part<<<PBLK, 256, 0, stream>>>(src, dst, bcursor, ppair);
    s4_build<<<NB, 256, 0, stream>>>(ppair, bcursor, row_info, dis, csr);
    k_xw<<<(N_NODES + XROWS - 1) / XROWS, 256, 0, stream>>>(x, W1, dis, hxs);
    k_agg1f<<<(N_NODES * 64 + 255) / 256, 256, 0, stream>>>(
        row_info, dis, (const unsigned*)hxs, csr, b1, W2, h2s);
    k_agg2f<<<(N_NODES * 16 + 255) / 256, 256, 0, stream>>>(
        row_info, dis, h2s, csr, b2, out);
}